// Round 1
// baseline (444.943 us; speedup 1.0000x reference)
//
#include <hip/hip_runtime.h>
#include <hip/hip_bf16.h>

#define T_TOK 2048
#define H_DIM 1024
#define I_DIM 4096
#define E_NUM 8

#define BM 128
#define BN 64
#define BK 64

typedef unsigned short u16;
typedef __bf16 bf16_t;
typedef bf16_t bf16x8 __attribute__((ext_vector_type(8)));
typedef float f32x4 __attribute__((ext_vector_type(4)));

__device__ __forceinline__ u16 f2bf(float f) {
  union { float f; unsigned u; } a; a.f = f;
  unsigned r = a.u + 0x7FFFu + ((a.u >> 16) & 1u);  // RNE
  return (u16)(r >> 16);
}

// ---------------- prep: zero out/counts, convert x -> bf16 ----------------
__global__ __launch_bounds__(256) void k_prep(const float* __restrict__ x,
                                              float* __restrict__ out,
                                              u16* __restrict__ xb,
                                              int* __restrict__ counts) {
  int i = blockIdx.x * 256 + threadIdx.x;           // 2048*256 threads, 4 floats each
  if (i < E_NUM) counts[i] = 0;
  float4 v = reinterpret_cast<const float4*>(x)[i];
  ushort4 b;
  b.x = f2bf(v.x); b.y = f2bf(v.y); b.z = f2bf(v.z); b.w = f2bf(v.w);
  reinterpret_cast<ushort4*>(xb)[i] = b;
  reinterpret_cast<float4*>(out)[i] = make_float4(0.f, 0.f, 0.f, 0.f);
}

// ---------------- router: fp32 logits, softcap, softmax, top-2 ----------------
__global__ __launch_bounds__(256) void k_router(const float* __restrict__ x,
                                                const float* __restrict__ gw,
                                                int* __restrict__ counts,
                                                int* __restrict__ ids,
                                                float* __restrict__ wts) {
  int gtid = blockIdx.x * 256 + threadIdx.x;
  int t = gtid >> 6;                                 // one wave per token
  int lane = threadIdx.x & 63;
  if (t >= T_TOK) return;
  const float* xr = x + (size_t)t * H_DIM;
  float4 xv[4];
#pragma unroll
  for (int j = 0; j < 4; ++j) xv[j] = reinterpret_cast<const float4*>(xr)[lane + 64 * j];
  float logit[E_NUM];
#pragma unroll
  for (int e = 0; e < E_NUM; ++e) {
    const float4* gr = reinterpret_cast<const float4*>(gw + (size_t)e * H_DIM);
    float s = 0.f;
#pragma unroll
    for (int j = 0; j < 4; ++j) {
      float4 g = gr[lane + 64 * j];
      s += xv[j].x * g.x + xv[j].y * g.y + xv[j].z * g.z + xv[j].w * g.w;
    }
#pragma unroll
    for (int off = 32; off; off >>= 1) s += __shfl_xor(s, off);
    logit[e] = s;
  }
  if (lane == 0) {
    float cap[E_NUM], mx = -1e30f;
#pragma unroll
    for (int e = 0; e < E_NUM; ++e) {
      cap[e] = 30.f * tanhf(logit[e] * (1.f / 30.f));
      mx = fmaxf(mx, cap[e]);
    }
    float p[E_NUM], sum = 0.f;
#pragma unroll
    for (int e = 0; e < E_NUM; ++e) { p[e] = expf(cap[e] - mx); sum += p[e]; }
    int i1 = 0; float p1 = p[0];
#pragma unroll
    for (int e = 1; e < E_NUM; ++e) if (p[e] > p1) { p1 = p[e]; i1 = e; }  // ties -> lowest idx
    int i2 = -1; float p2 = -1.f;
#pragma unroll
    for (int e = 0; e < E_NUM; ++e) if (e != i1 && p[e] > p2) { p2 = p[e]; i2 = e; }
    float inv = 1.f / sum;
    int s1 = atomicAdd(&counts[i1], 1);
    ids[i1 * T_TOK + s1] = t; wts[i1 * T_TOK + s1] = p1 * inv;
    int s2 = atomicAdd(&counts[i2], 1);
    ids[i2 * T_TOK + s2] = t; wts[i2 * T_TOK + s2] = p2 * inv;
  }
}

// ---------------- tiny exclusive scan over 8 expert counts ----------------
__global__ void k_offs(const int* __restrict__ counts, int* __restrict__ offs) {
  if (threadIdx.x == 0) {
    int a = 0;
    for (int e = 0; e < E_NUM; ++e) { offs[e] = a; a += counts[e]; }
  }
}

// ---------------- fused gate/up GEMM + erf-GELU -> h (bf16) ----------------
__global__ __launch_bounds__(256) void k_gateup(
    const u16* __restrict__ xb, const float* __restrict__ w1g, const float* __restrict__ w1u,
    const int* __restrict__ counts, const int* __restrict__ offs, const int* __restrict__ ids,
    u16* __restrict__ h) {
  const int e = blockIdx.z, mt = blockIdx.y, nt = blockIdx.x;
  const int cnt = counts[e];
  if (mt * BM >= cnt) return;
  __shared__ u16 As[BM * BK];
  __shared__ u16 Bg[BN * BK];
  __shared__ u16 Bu[BN * BK];
  const int tid = threadIdx.x, lane = tid & 63, wid = tid >> 6;
  const int wr = (wid >> 1) * 64, wc = (wid & 1) * 32;
  const int lr = lane & 15, lk = lane >> 4;
  const int i0 = nt * BN;

  f32x4 accg[4][2], accu[4][2];
#pragma unroll
  for (int mi = 0; mi < 4; ++mi)
#pragma unroll
    for (int ni = 0; ni < 2; ++ni) { accg[mi][ni] = (f32x4)0.f; accu[mi][ni] = (f32x4)0.f; }

  int atok[4];
#pragma unroll
  for (int it = 0; it < 4; ++it) {
    int rg = mt * BM + ((tid + it * 256) >> 3);
    if (rg >= cnt) rg = cnt - 1;                 // clamp: rows past count discarded later
    atok[it] = ids[e * T_TOK + rg];
  }

  for (int kt = 0; kt < H_DIM / BK; ++kt) {
    const int k0 = kt * BK;
#pragma unroll
    for (int it = 0; it < 4; ++it) {             // A: 128 rows x 8 granules(16B)
      int idx = tid + it * 256;
      int r = idx >> 3, g = idx & 7;
      uint4 v = *reinterpret_cast<const uint4*>(xb + (size_t)atok[it] * H_DIM + k0 + g * 8);
      *reinterpret_cast<uint4*>(&As[r * BK + ((g ^ (r & 7)) << 3)]) = v;
    }
#pragma unroll
    for (int it = 0; it < 2; ++it) {             // Bg/Bu: 64 rows x 8 granules, fp32->bf16
      int idx = tid + it * 256;
      int r = idx >> 3, g = idx & 7;
      size_t gofs = (size_t)(e * I_DIM + i0 + r) * H_DIM + k0 + g * 8;
      {
        float4 f0 = *reinterpret_cast<const float4*>(w1g + gofs);
        float4 f1 = *reinterpret_cast<const float4*>(w1g + gofs + 4);
        union { uint4 u; u16 s[8]; } pk;
        pk.s[0] = f2bf(f0.x); pk.s[1] = f2bf(f0.y); pk.s[2] = f2bf(f0.z); pk.s[3] = f2bf(f0.w);
        pk.s[4] = f2bf(f1.x); pk.s[5] = f2bf(f1.y); pk.s[6] = f2bf(f1.z); pk.s[7] = f2bf(f1.w);
        *reinterpret_cast<uint4*>(&Bg[r * BK + ((g ^ (r & 7)) << 3)]) = pk.u;
      }
      {
        float4 f0 = *reinterpret_cast<const float4*>(w1u + gofs);
        float4 f1 = *reinterpret_cast<const float4*>(w1u + gofs + 4);
        union { uint4 u; u16 s[8]; } pk;
        pk.s[0] = f2bf(f0.x); pk.s[1] = f2bf(f0.y); pk.s[2] = f2bf(f0.z); pk.s[3] = f2bf(f0.w);
        pk.s[4] = f2bf(f1.x); pk.s[5] = f2bf(f1.y); pk.s[6] = f2bf(f1.z); pk.s[7] = f2bf(f1.w);
        *reinterpret_cast<uint4*>(&Bu[r * BK + ((g ^ (r & 7)) << 3)]) = pk.u;
      }
    }
    __syncthreads();
#pragma unroll
    for (int kk = 0; kk < 2; ++kk) {
      const int colg = kk * 4 + lk;
      bf16x8 a[4], bg[2], bu[2];
#pragma unroll
      for (int mi = 0; mi < 4; ++mi) {
        int r = wr + mi * 16 + lr;
        a[mi] = *reinterpret_cast<const bf16x8*>(&As[r * BK + ((colg ^ (r & 7)) << 3)]);
      }
#pragma unroll
      for (int ni = 0; ni < 2; ++ni) {
        int r = wc + ni * 16 + lr;
        bg[ni] = *reinterpret_cast<const bf16x8*>(&Bg[r * BK + ((colg ^ (r & 7)) << 3)]);
        bu[ni] = *reinterpret_cast<const bf16x8*>(&Bu[r * BK + ((colg ^ (r & 7)) << 3)]);
      }
#pragma unroll
      for (int mi = 0; mi < 4; ++mi)
#pragma unroll
        for (int ni = 0; ni < 2; ++ni) {
          accg[mi][ni] = __builtin_amdgcn_mfma_f32_16x16x32_bf16(a[mi], bg[ni], accg[mi][ni], 0, 0, 0);
          accu[mi][ni] = __builtin_amdgcn_mfma_f32_16x16x32_bf16(a[mi], bu[ni], accu[mi][ni], 0, 0, 0);
        }
    }
    __syncthreads();
  }
  const int hbase = offs[e];
#pragma unroll
  for (int mi = 0; mi < 4; ++mi)
#pragma unroll
    for (int rr = 0; rr < 4; ++rr) {
      int grow = mt * BM + wr + mi * 16 + lk * 4 + rr;   // C/D: row=(lane>>4)*4+reg
      if (grow < cnt) {
        size_t hrow = (size_t)(hbase + grow) * I_DIM;
#pragma unroll
        for (int ni = 0; ni < 2; ++ni) {
          int col = i0 + wc + ni * 16 + lr;              // C/D: col=lane&15
          float g = accg[mi][ni][rr];
          float u = accu[mi][ni][rr];
          float act = 0.5f * g * (1.f + erff(g * 0.70710678118f));  // exact GELU
          h[hrow + col] = f2bf(act * u);
        }
      }
    }
}

// ---------------- down GEMM + weighted scatter-add ----------------
__global__ __launch_bounds__(256) void k_down(
    const u16* __restrict__ h, const float* __restrict__ w2,
    const int* __restrict__ counts, const int* __restrict__ offs, const int* __restrict__ ids,
    const float* __restrict__ wts, float* __restrict__ out) {
  const int e = blockIdx.z, mt = blockIdx.y, nt = blockIdx.x;
  const int cnt = counts[e];
  if (mt * BM >= cnt) return;
  __shared__ u16 As[BM * BK];
  __shared__ u16 Bs[BN * BK];
  const int tid = threadIdx.x, lane = tid & 63, wid = tid >> 6;
  const int wr = (wid >> 1) * 64, wc = (wid & 1) * 32;
  const int lr = lane & 15, lk = lane >> 4;
  const int n0 = nt * BN;
  const int hbase = offs[e];

  f32x4 acc[4][2];
#pragma unroll
  for (int mi = 0; mi < 4; ++mi)
#pragma unroll
    for (int ni = 0; ni < 2; ++ni) acc[mi][ni] = (f32x4)0.f;

  int arow[4];
#pragma unroll
  for (int it = 0; it < 4; ++it) {
    int rg = mt * BM + ((tid + it * 256) >> 3);
    if (rg >= cnt) rg = cnt - 1;
    arow[it] = hbase + rg;
  }

  for (int kt = 0; kt < I_DIM / BK; ++kt) {
    const int k0 = kt * BK;
#pragma unroll
    for (int it = 0; it < 4; ++it) {
      int idx = tid + it * 256;
      int r = idx >> 3, g = idx & 7;
      uint4 v = *reinterpret_cast<const uint4*>(h + (size_t)arow[it] * I_DIM + k0 + g * 8);
      *reinterpret_cast<uint4*>(&As[r * BK + ((g ^ (r & 7)) << 3)]) = v;
    }
#pragma unroll
    for (int it = 0; it < 2; ++it) {
      int idx = tid + it * 256;
      int r = idx >> 3, g = idx & 7;
      size_t gofs = (size_t)(e * H_DIM + n0 + r) * I_DIM + k0 + g * 8;
      float4 f0 = *reinterpret_cast<const float4*>(w2 + gofs);
      float4 f1 = *reinterpret_cast<const float4*>(w2 + gofs + 4);
      union { uint4 u; u16 s[8]; } pk;
      pk.s[0] = f2bf(f0.x); pk.s[1] = f2bf(f0.y); pk.s[2] = f2bf(f0.z); pk.s[3] = f2bf(f0.w);
      pk.s[4] = f2bf(f1.x); pk.s[5] = f2bf(f1.y); pk.s[6] = f2bf(f1.z); pk.s[7] = f2bf(f1.w);
      *reinterpret_cast<uint4*>(&Bs[r * BK + ((g ^ (r & 7)) << 3)]) = pk.u;
    }
    __syncthreads();
#pragma unroll
    for (int kk = 0; kk < 2; ++kk) {
      const int colg = kk * 4 + lk;
      bf16x8 a[4], b[2];
#pragma unroll
      for (int mi = 0; mi < 4; ++mi) {
        int r = wr + mi * 16 + lr;
        a[mi] = *reinterpret_cast<const bf16x8*>(&As[r * BK + ((colg ^ (r & 7)) << 3)]);
      }
#pragma unroll
      for (int ni = 0; ni < 2; ++ni) {
        int r = wc + ni * 16 + lr;
        b[ni] = *reinterpret_cast<const bf16x8*>(&Bs[r * BK + ((colg ^ (r & 7)) << 3)]);
      }
#pragma unroll
      for (int mi = 0; mi < 4; ++mi)
#pragma unroll
        for (int ni = 0; ni < 2; ++ni)
          acc[mi][ni] = __builtin_amdgcn_mfma_f32_16x16x32_bf16(a[mi], b[ni], acc[mi][ni], 0, 0, 0);
    }
    __syncthreads();
  }
#pragma unroll
  for (int mi = 0; mi < 4; ++mi)
#pragma unroll
    for (int rr = 0; rr < 4; ++rr) {
      int grow = mt * BM + wr + mi * 16 + lk * 4 + rr;
      if (grow < cnt) {
        int tok = ids[e * T_TOK + grow];
        float w = wts[e * T_TOK + grow];
#pragma unroll
        for (int ni = 0; ni < 2; ++ni) {
          int col = n0 + wc + ni * 16 + lr;
          atomicAdd(&out[(size_t)tok * H_DIM + col], w * acc[mi][ni][rr]);
        }
      }
    }
}

extern "C" void kernel_launch(void* const* d_in, const int* in_sizes, int n_in,
                              void* d_out, int out_size, void* d_ws, size_t ws_size,
                              hipStream_t stream) {
  const float* x   = (const float*)d_in[0];
  const float* gw  = (const float*)d_in[1];
  const float* w1g = (const float*)d_in[2];
  const float* w1u = (const float*)d_in[3];
  const float* w2  = (const float*)d_in[4];
  float* out = (float*)d_out;
  char* ws = (char*)d_ws;
  // ws layout: xb 4MB | h 32MB | ids 64KB | wts 64KB | counts/offs
  u16* xb    = (u16*)ws;
  u16* h     = (u16*)(ws + (4u << 20));
  int* ids   = (int*)(ws + (4u << 20) + (32u << 20));
  float* wts = (float*)(ws + (4u << 20) + (32u << 20) + (64u << 10));
  int* counts = (int*)(ws + (4u << 20) + (32u << 20) + (128u << 10));
  int* offs   = counts + 8;

  k_prep<<<2048, 256, 0, stream>>>(x, out, xb, counts);
  k_router<<<512, 256, 0, stream>>>(x, gw, counts, ids, wts);
  k_offs<<<1, 64, 0, stream>>>(counts, offs);
  k_gateup<<<dim3(I_DIM / BN, T_TOK / BM, E_NUM), 256, 0, stream>>>(xb, w1g, w1u, counts, offs, ids, h);
  k_down<<<dim3(H_DIM / BN, T_TOK / BM, E_NUM), 256, 0, stream>>>(h, w2, counts, offs, ids, wts, out);
}

// Round 2
// 423.130 us; speedup vs baseline: 1.0516x; 1.0516x over previous
//
#include <hip/hip_runtime.h>
#include <hip/hip_bf16.h>
#include <stdint.h>

#define T_TOK 2048
#define H_DIM 1024
#define I_DIM 4096
#define E_NUM 8

#define BM 128
#define BN 64
#define BK 64
#define KS 4            // split-K factor for k_down2 (I_DIM/BK/KS = 16 iters/block)

typedef unsigned short u16;
typedef __bf16 bf16_t;
typedef bf16_t bf16x8 __attribute__((ext_vector_type(8)));
typedef float f32x4 __attribute__((ext_vector_type(4)));

__device__ __forceinline__ u16 f2bf(float f) {
  union { float f; unsigned u; } a; a.f = f;
  unsigned r = a.u + 0x7FFFu + ((a.u >> 16) & 1u);  // RNE
  return (u16)(r >> 16);
}

__device__ __forceinline__ void gload_lds16(const void* g, void* l) {
  __builtin_amdgcn_global_load_lds(
      (const __attribute__((address_space(1))) void*)g,
      (__attribute__((address_space(3))) void*)l, 16, 0, 0);
}

// ---------------- prep: zero out/counts, convert x -> bf16 ----------------
__global__ __launch_bounds__(256) void k_prep(const float* __restrict__ x,
                                              float* __restrict__ out,
                                              u16* __restrict__ xb,
                                              int* __restrict__ counts) {
  int i = blockIdx.x * 256 + threadIdx.x;           // 2048*256 threads, 4 floats each
  if (i < E_NUM) counts[i] = 0;
  float4 v = reinterpret_cast<const float4*>(x)[i];
  ushort4 b;
  b.x = f2bf(v.x); b.y = f2bf(v.y); b.z = f2bf(v.z); b.w = f2bf(v.w);
  reinterpret_cast<ushort4*>(xb)[i] = b;
  reinterpret_cast<float4*>(out)[i] = make_float4(0.f, 0.f, 0.f, 0.f);
}

// ---------------- streaming fp32 -> bf16 weight conversion ----------------
__global__ __launch_bounds__(256) void k_cvt(const float* __restrict__ src,
                                             u16* __restrict__ dst, int n4) {
  int stride = gridDim.x * 256;
  for (int i = blockIdx.x * 256 + threadIdx.x; i < n4; i += stride) {
    float4 v = reinterpret_cast<const float4*>(src)[i];
    ushort4 b;
    b.x = f2bf(v.x); b.y = f2bf(v.y); b.z = f2bf(v.z); b.w = f2bf(v.w);
    reinterpret_cast<ushort4*>(dst)[i] = b;
  }
}

// ---------------- router: fp32 logits, softcap, softmax, top-2 ----------------
__global__ __launch_bounds__(256) void k_router(const float* __restrict__ x,
                                                const float* __restrict__ gw,
                                                int* __restrict__ counts,
                                                int* __restrict__ ids,
                                                float* __restrict__ wts) {
  int gtid = blockIdx.x * 256 + threadIdx.x;
  int t = gtid >> 6;                                 // one wave per token
  int lane = threadIdx.x & 63;
  if (t >= T_TOK) return;
  const float* xr = x + (size_t)t * H_DIM;
  float4 xv[4];
#pragma unroll
  for (int j = 0; j < 4; ++j) xv[j] = reinterpret_cast<const float4*>(xr)[lane + 64 * j];
  float logit[E_NUM];
#pragma unroll
  for (int e = 0; e < E_NUM; ++e) {
    const float4* gr = reinterpret_cast<const float4*>(gw + (size_t)e * H_DIM);
    float s = 0.f;
#pragma unroll
    for (int j = 0; j < 4; ++j) {
      float4 g = gr[lane + 64 * j];
      s += xv[j].x * g.x + xv[j].y * g.y + xv[j].z * g.z + xv[j].w * g.w;
    }
#pragma unroll
    for (int off = 32; off; off >>= 1) s += __shfl_xor(s, off);
    logit[e] = s;
  }
  if (lane == 0) {
    float cap[E_NUM], mx = -1e30f;
#pragma unroll
    for (int e = 0; e < E_NUM; ++e) {
      cap[e] = 30.f * tanhf(logit[e] * (1.f / 30.f));
      mx = fmaxf(mx, cap[e]);
    }
    float p[E_NUM], sum = 0.f;
#pragma unroll
    for (int e = 0; e < E_NUM; ++e) { p[e] = expf(cap[e] - mx); sum += p[e]; }
    int i1 = 0; float p1 = p[0];
#pragma unroll
    for (int e = 1; e < E_NUM; ++e) if (p[e] > p1) { p1 = p[e]; i1 = e; }  // ties -> lowest idx
    int i2 = -1; float p2 = -1.f;
#pragma unroll
    for (int e = 0; e < E_NUM; ++e) if (e != i1 && p[e] > p2) { p2 = p[e]; i2 = e; }
    float inv = 1.f / sum;
    int s1 = atomicAdd(&counts[i1], 1);
    ids[i1 * T_TOK + s1] = t; wts[i1 * T_TOK + s1] = p1 * inv;
    int s2 = atomicAdd(&counts[i2], 1);
    ids[i2 * T_TOK + s2] = t; wts[i2 * T_TOK + s2] = p2 * inv;
  }
}

// ---------------- tiny exclusive scan over 8 expert counts ----------------
__global__ void k_offs(const int* __restrict__ counts, int* __restrict__ offs) {
  if (threadIdx.x == 0) {
    int a = 0;
    for (int e = 0; e < E_NUM; ++e) { offs[e] = a; a += counts[e]; }
  }
}

// ===================== NEW PATH: bf16 weights + global_load_lds =====================

// fused gate/up GEMM + erf-GELU -> h (bf16); m97-style staging
__global__ __launch_bounds__(256) void k_gateup2(
    const u16* __restrict__ xb, const u16* __restrict__ w1gb, const u16* __restrict__ w1ub,
    const int* __restrict__ counts, const int* __restrict__ offs, const int* __restrict__ ids,
    u16* __restrict__ h) {
  const int e = blockIdx.z, mt = blockIdx.y, nt = blockIdx.x;
  const int cnt = counts[e];
  if (mt * BM >= cnt) return;
  __shared__ u16 As[BM * BK];   // [128][64] linear (global_load_lds requires linear)
  __shared__ u16 Bg[BN * BK];   // [64][64]
  __shared__ u16 Bu[BN * BK];
  const int tid = threadIdx.x, lane = tid & 63, wid = tid >> 6;
  const int wr = (wid >> 1) * 64, wc = (wid & 1) * 32;
  const int lr = lane & 15, lk = lane >> 4;
  const int i0 = nt * BN;
  const int lrow = lane >> 3, lg = lane & 7;   // staging: 8 lanes/row, 16B granule

  // per-lane global source bases (advance by BK elems per kt)
  const u16* asrc[4];
#pragma unroll
  for (int i = 0; i < 4; ++i) {
    int rg = mt * BM + wid * 32 + i * 8 + lrow;
    if (rg >= cnt) rg = cnt - 1;
    asrc[i] = xb + (size_t)ids[e * T_TOK + rg] * H_DIM + lg * 8;
  }
  const u16 *gsrc[2], *usrc[2];
#pragma unroll
  for (int i = 0; i < 2; ++i) {
    size_t o = (size_t)(e * I_DIM + i0 + wid * 16 + i * 8 + lrow) * H_DIM + lg * 8;
    gsrc[i] = w1gb + o; usrc[i] = w1ub + o;
  }
  u16* aldsb = As + (wid * 32) * BK;   // wave-uniform LDS bases
  u16* gldsb = Bg + (wid * 16) * BK;
  u16* uldsb = Bu + (wid * 16) * BK;

  f32x4 accg[4][2], accu[4][2];
#pragma unroll
  for (int mi = 0; mi < 4; ++mi)
#pragma unroll
    for (int ni = 0; ni < 2; ++ni) { accg[mi][ni] = (f32x4)0.f; accu[mi][ni] = (f32x4)0.f; }

  for (int kt = 0; kt < H_DIM / BK; ++kt) {
    const int ko = kt * BK;
#pragma unroll
    for (int i = 0; i < 4; ++i) gload_lds16(asrc[i] + ko, aldsb + i * 8 * BK);
#pragma unroll
    for (int i = 0; i < 2; ++i) {
      gload_lds16(gsrc[i] + ko, gldsb + i * 8 * BK);
      gload_lds16(usrc[i] + ko, uldsb + i * 8 * BK);
    }
    __syncthreads();
#pragma unroll
    for (int kk = 0; kk < 2; ++kk) {
      const int colg = kk * 4 + lk;
      bf16x8 a[4], bg[2], bu[2];
#pragma unroll
      for (int mi = 0; mi < 4; ++mi)
        a[mi] = *reinterpret_cast<const bf16x8*>(&As[(wr + mi * 16 + lr) * BK + colg * 8]);
#pragma unroll
      for (int ni = 0; ni < 2; ++ni) {
        bg[ni] = *reinterpret_cast<const bf16x8*>(&Bg[(wc + ni * 16 + lr) * BK + colg * 8]);
        bu[ni] = *reinterpret_cast<const bf16x8*>(&Bu[(wc + ni * 16 + lr) * BK + colg * 8]);
      }
#pragma unroll
      for (int mi = 0; mi < 4; ++mi)
#pragma unroll
        for (int ni = 0; ni < 2; ++ni) {
          accg[mi][ni] = __builtin_amdgcn_mfma_f32_16x16x32_bf16(a[mi], bg[ni], accg[mi][ni], 0, 0, 0);
          accu[mi][ni] = __builtin_amdgcn_mfma_f32_16x16x32_bf16(a[mi], bu[ni], accu[mi][ni], 0, 0, 0);
        }
    }
    __syncthreads();
  }
  const int hbase = offs[e];
#pragma unroll
  for (int mi = 0; mi < 4; ++mi)
#pragma unroll
    for (int rr = 0; rr < 4; ++rr) {
      int grow = mt * BM + wr + mi * 16 + lk * 4 + rr;   // C/D: row=(lane>>4)*4+reg
      if (grow < cnt) {
        size_t hrow = (size_t)(hbase + grow) * I_DIM;
#pragma unroll
        for (int ni = 0; ni < 2; ++ni) {
          int col = i0 + wc + ni * 16 + lr;              // C/D: col=lane&15
          float g = accg[mi][ni][rr];
          float u = accu[mi][ni][rr];
          float act = 0.5f * g * (1.f + erff(g * 0.70710678118f));  // exact GELU
          h[hrow + col] = f2bf(act * u);
        }
      }
    }
}

// down GEMM (split-K) + weighted scatter-add
__global__ __launch_bounds__(256) void k_down2(
    const u16* __restrict__ h, const u16* __restrict__ w2b,
    const int* __restrict__ counts, const int* __restrict__ offs, const int* __restrict__ ids,
    const float* __restrict__ wts, float* __restrict__ out) {
  const int e = blockIdx.z, mt = blockIdx.y;
  const int nt = blockIdx.x & 15, ks = blockIdx.x >> 4;
  const int cnt = counts[e];
  if (mt * BM >= cnt) return;
  __shared__ u16 As[BM * BK];
  __shared__ u16 Bs[BN * BK];
  const int tid = threadIdx.x, lane = tid & 63, wid = tid >> 6;
  const int wr = (wid >> 1) * 64, wc = (wid & 1) * 32;
  const int lr = lane & 15, lk = lane >> 4;
  const int n0 = nt * BN;
  const int hbase = offs[e];
  const int lrow = lane >> 3, lg = lane & 7;

  const u16* asrc[4];
#pragma unroll
  for (int i = 0; i < 4; ++i) {
    int rg = mt * BM + wid * 32 + i * 8 + lrow;
    if (rg >= cnt) rg = cnt - 1;
    asrc[i] = h + (size_t)(hbase + rg) * I_DIM + lg * 8;
  }
  const u16* bsrc[2];
#pragma unroll
  for (int i = 0; i < 2; ++i)
    bsrc[i] = w2b + (size_t)(e * H_DIM + n0 + wid * 16 + i * 8 + lrow) * I_DIM + lg * 8;
  u16* aldsb = As + (wid * 32) * BK;
  u16* bldsb = Bs + (wid * 16) * BK;

  f32x4 acc[4][2];
#pragma unroll
  for (int mi = 0; mi < 4; ++mi)
#pragma unroll
    for (int ni = 0; ni < 2; ++ni) acc[mi][ni] = (f32x4)0.f;

  const int KT = I_DIM / BK / KS;            // 16 iters per block
  for (int kt = ks * KT; kt < (ks + 1) * KT; ++kt) {
    const int ko = kt * BK;
#pragma unroll
    for (int i = 0; i < 4; ++i) gload_lds16(asrc[i] + ko, aldsb + i * 8 * BK);
#pragma unroll
    for (int i = 0; i < 2; ++i) gload_lds16(bsrc[i] + ko, bldsb + i * 8 * BK);
    __syncthreads();
#pragma unroll
    for (int kk = 0; kk < 2; ++kk) {
      const int colg = kk * 4 + lk;
      bf16x8 a[4], b[2];
#pragma unroll
      for (int mi = 0; mi < 4; ++mi)
        a[mi] = *reinterpret_cast<const bf16x8*>(&As[(wr + mi * 16 + lr) * BK + colg * 8]);
#pragma unroll
      for (int ni = 0; ni < 2; ++ni)
        b[ni] = *reinterpret_cast<const bf16x8*>(&Bs[(wc + ni * 16 + lr) * BK + colg * 8]);
#pragma unroll
      for (int mi = 0; mi < 4; ++mi)
#pragma unroll
        for (int ni = 0; ni < 2; ++ni)
          acc[mi][ni] = __builtin_amdgcn_mfma_f32_16x16x32_bf16(a[mi], b[ni], acc[mi][ni], 0, 0, 0);
    }
    __syncthreads();
  }
#pragma unroll
  for (int mi = 0; mi < 4; ++mi)
#pragma unroll
    for (int rr = 0; rr < 4; ++rr) {
      int grow = mt * BM + wr + mi * 16 + lk * 4 + rr;
      if (grow < cnt) {
        int tok = ids[e * T_TOK + grow];
        float w = wts[e * T_TOK + grow];
#pragma unroll
        for (int ni = 0; ni < 2; ++ni) {
          int col = n0 + wc + ni * 16 + lr;
          atomicAdd(&out[(size_t)tok * H_DIM + col], w * acc[mi][ni][rr]);
        }
      }
    }
}

// ===================== FALLBACK PATH (round-1, fp32 weights in GEMM) =====================

__global__ __launch_bounds__(256) void k_gateup(
    const u16* __restrict__ xb, const float* __restrict__ w1g, const float* __restrict__ w1u,
    const int* __restrict__ counts, const int* __restrict__ offs, const int* __restrict__ ids,
    u16* __restrict__ h) {
  const int e = blockIdx.z, mt = blockIdx.y, nt = blockIdx.x;
  const int cnt = counts[e];
  if (mt * BM >= cnt) return;
  __shared__ u16 As[BM * BK];
  __shared__ u16 Bg[BN * BK];
  __shared__ u16 Bu[BN * BK];
  const int tid = threadIdx.x, lane = tid & 63, wid = tid >> 6;
  const int wr = (wid >> 1) * 64, wc = (wid & 1) * 32;
  const int lr = lane & 15, lk = lane >> 4;
  const int i0 = nt * BN;

  f32x4 accg[4][2], accu[4][2];
#pragma unroll
  for (int mi = 0; mi < 4; ++mi)
#pragma unroll
    for (int ni = 0; ni < 2; ++ni) { accg[mi][ni] = (f32x4)0.f; accu[mi][ni] = (f32x4)0.f; }

  int atok[4];
#pragma unroll
  for (int it = 0; it < 4; ++it) {
    int rg = mt * BM + ((tid + it * 256) >> 3);
    if (rg >= cnt) rg = cnt - 1;
    atok[it] = ids[e * T_TOK + rg];
  }

  for (int kt = 0; kt < H_DIM / BK; ++kt) {
    const int k0 = kt * BK;
#pragma unroll
    for (int it = 0; it < 4; ++it) {
      int idx = tid + it * 256;
      int r = idx >> 3, g = idx & 7;
      uint4 v = *reinterpret_cast<const uint4*>(xb + (size_t)atok[it] * H_DIM + k0 + g * 8);
      *reinterpret_cast<uint4*>(&As[r * BK + ((g ^ (r & 7)) << 3)]) = v;
    }
#pragma unroll
    for (int it = 0; it < 2; ++it) {
      int idx = tid + it * 256;
      int r = idx >> 3, g = idx & 7;
      size_t gofs = (size_t)(e * I_DIM + i0 + r) * H_DIM + k0 + g * 8;
      {
        float4 f0 = *reinterpret_cast<const float4*>(w1g + gofs);
        float4 f1 = *reinterpret_cast<const float4*>(w1g + gofs + 4);
        union { uint4 u; u16 s[8]; } pk;
        pk.s[0] = f2bf(f0.x); pk.s[1] = f2bf(f0.y); pk.s[2] = f2bf(f0.z); pk.s[3] = f2bf(f0.w);
        pk.s[4] = f2bf(f1.x); pk.s[5] = f2bf(f1.y); pk.s[6] = f2bf(f1.z); pk.s[7] = f2bf(f1.w);
        *reinterpret_cast<uint4*>(&Bg[r * BK + ((g ^ (r & 7)) << 3)]) = pk.u;
      }
      {
        float4 f0 = *reinterpret_cast<const float4*>(w1u + gofs);
        float4 f1 = *reinterpret_cast<const float4*>(w1u + gofs + 4);
        union { uint4 u; u16 s[8]; } pk;
        pk.s[0] = f2bf(f0.x); pk.s[1] = f2bf(f0.y); pk.s[2] = f2bf(f0.z); pk.s[3] = f2bf(f0.w);
        pk.s[4] = f2bf(f1.x); pk.s[5] = f2bf(f1.y); pk.s[6] = f2bf(f1.z); pk.s[7] = f2bf(f1.w);
        *reinterpret_cast<uint4*>(&Bu[r * BK + ((g ^ (r & 7)) << 3)]) = pk.u;
      }
    }
    __syncthreads();
#pragma unroll
    for (int kk = 0; kk < 2; ++kk) {
      const int colg = kk * 4 + lk;
      bf16x8 a[4], bg[2], bu[2];
#pragma unroll
      for (int mi = 0; mi < 4; ++mi) {
        int r = wr + mi * 16 + lr;
        a[mi] = *reinterpret_cast<const bf16x8*>(&As[r * BK + ((colg ^ (r & 7)) << 3)]);
      }
#pragma unroll
      for (int ni = 0; ni < 2; ++ni) {
        int r = wc + ni * 16 + lr;
        bg[ni] = *reinterpret_cast<const bf16x8*>(&Bg[r * BK + ((colg ^ (r & 7)) << 3)]);
        bu[ni] = *reinterpret_cast<const bf16x8*>(&Bu[r * BK + ((colg ^ (r & 7)) << 3)]);
      }
#pragma unroll
      for (int mi = 0; mi < 4; ++mi)
#pragma unroll
        for (int ni = 0; ni < 2; ++ni) {
          accg[mi][ni] = __builtin_amdgcn_mfma_f32_16x16x32_bf16(a[mi], bg[ni], accg[mi][ni], 0, 0, 0);
          accu[mi][ni] = __builtin_amdgcn_mfma_f32_16x16x32_bf16(a[mi], bu[ni], accu[mi][ni], 0, 0, 0);
        }
    }
    __syncthreads();
  }
  const int hbase = offs[e];
#pragma unroll
  for (int mi = 0; mi < 4; ++mi)
#pragma unroll
    for (int rr = 0; rr < 4; ++rr) {
      int grow = mt * BM + wr + mi * 16 + lk * 4 + rr;
      if (grow < cnt) {
        size_t hrow = (size_t)(hbase + grow) * I_DIM;
#pragma unroll
        for (int ni = 0; ni < 2; ++ni) {
          int col = i0 + wc + ni * 16 + lr;
          float g = accg[mi][ni][rr];
          float u = accu[mi][ni][rr];
          float act = 0.5f * g * (1.f + erff(g * 0.70710678118f));
          h[hrow + col] = f2bf(act * u);
        }
      }
    }
}

__global__ __launch_bounds__(256) void k_down(
    const u16* __restrict__ h, const float* __restrict__ w2,
    const int* __restrict__ counts, const int* __restrict__ offs, const int* __restrict__ ids,
    const float* __restrict__ wts, float* __restrict__ out) {
  const int e = blockIdx.z, mt = blockIdx.y, nt = blockIdx.x;
  const int cnt = counts[e];
  if (mt * BM >= cnt) return;
  __shared__ u16 As[BM * BK];
  __shared__ u16 Bs[BN * BK];
  const int tid = threadIdx.x, lane = tid & 63, wid = tid >> 6;
  const int wr = (wid >> 1) * 64, wc = (wid & 1) * 32;
  const int lr = lane & 15, lk = lane >> 4;
  const int n0 = nt * BN;
  const int hbase = offs[e];

  f32x4 acc[4][2];
#pragma unroll
  for (int mi = 0; mi < 4; ++mi)
#pragma unroll
    for (int ni = 0; ni < 2; ++ni) acc[mi][ni] = (f32x4)0.f;

  int arow[4];
#pragma unroll
  for (int it = 0; it < 4; ++it) {
    int rg = mt * BM + ((tid + it * 256) >> 3);
    if (rg >= cnt) rg = cnt - 1;
    arow[it] = hbase + rg;
  }

  for (int kt = 0; kt < I_DIM / BK; ++kt) {
    const int k0 = kt * BK;
#pragma unroll
    for (int it = 0; it < 4; ++it) {
      int idx = tid + it * 256;
      int r = idx >> 3, g = idx & 7;
      uint4 v = *reinterpret_cast<const uint4*>(h + (size_t)arow[it] * I_DIM + k0 + g * 8);
      *reinterpret_cast<uint4*>(&As[r * BK + ((g ^ (r & 7)) << 3)]) = v;
    }
#pragma unroll
    for (int it = 0; it < 2; ++it) {
      int idx = tid + it * 256;
      int r = idx >> 3, g = idx & 7;
      size_t gofs = (size_t)(e * H_DIM + n0 + r) * I_DIM + k0 + g * 8;
      float4 f0 = *reinterpret_cast<const float4*>(w2 + gofs);
      float4 f1 = *reinterpret_cast<const float4*>(w2 + gofs + 4);
      union { uint4 u; u16 s[8]; } pk;
      pk.s[0] = f2bf(f0.x); pk.s[1] = f2bf(f0.y); pk.s[2] = f2bf(f0.z); pk.s[3] = f2bf(f0.w);
      pk.s[4] = f2bf(f1.x); pk.s[5] = f2bf(f1.y); pk.s[6] = f2bf(f1.z); pk.s[7] = f2bf(f1.w);
      *reinterpret_cast<uint4*>(&Bs[r * BK + ((g ^ (r & 7)) << 3)]) = pk.u;
    }
    __syncthreads();
#pragma unroll
    for (int kk = 0; kk < 2; ++kk) {
      const int colg = kk * 4 + lk;
      bf16x8 a[4], b[2];
#pragma unroll
      for (int mi = 0; mi < 4; ++mi) {
        int r = wr + mi * 16 + lr;
        a[mi] = *reinterpret_cast<const bf16x8*>(&As[r * BK + ((colg ^ (r & 7)) << 3)]);
      }
#pragma unroll
      for (int ni = 0; ni < 2; ++ni) {
        int r = wc + ni * 16 + lr;
        b[ni] = *reinterpret_cast<const bf16x8*>(&Bs[r * BK + ((colg ^ (r & 7)) << 3)]);
      }
#pragma unroll
      for (int mi = 0; mi < 4; ++mi)
#pragma unroll
        for (int ni = 0; ni < 2; ++ni)
          acc[mi][ni] = __builtin_amdgcn_mfma_f32_16x16x32_bf16(a[mi], b[ni], acc[mi][ni], 0, 0, 0);
    }
    __syncthreads();
  }
#pragma unroll
  for (int mi = 0; mi < 4; ++mi)
#pragma unroll
    for (int rr = 0; rr < 4; ++rr) {
      int grow = mt * BM + wr + mi * 16 + lk * 4 + rr;
      if (grow < cnt) {
        int tok = ids[e * T_TOK + grow];
        float w = wts[e * T_TOK + grow];
#pragma unroll
        for (int ni = 0; ni < 2; ++ni) {
          int col = n0 + wc + ni * 16 + lr;
          atomicAdd(&out[(size_t)tok * H_DIM + col], w * acc[mi][ni][rr]);
        }
      }
    }
}

extern "C" void kernel_launch(void* const* d_in, const int* in_sizes, int n_in,
                              void* d_out, int out_size, void* d_ws, size_t ws_size,
                              hipStream_t stream) {
  const float* x   = (const float*)d_in[0];
  const float* gw  = (const float*)d_in[1];
  const float* w1g = (const float*)d_in[2];
  const float* w1u = (const float*)d_in[3];
  const float* w2  = (const float*)d_in[4];
  float* out = (float*)d_out;
  char* ws = (char*)d_ws;

  const size_t MB = 1u << 20;
  // new-path layout
  const size_t OFF_XB  = 0;
  const size_t OFF_H   = 4 * MB;
  const size_t OFF_W1G = OFF_H + 32 * MB;
  const size_t OFF_W1U = OFF_W1G + 64 * MB;
  const size_t OFF_W2  = OFF_W1U + 64 * MB;
  const size_t OFF_IDS = OFF_W2 + 64 * MB;
  const size_t OFF_WTS = OFF_IDS + (64u << 10);
  const size_t OFF_CNT = OFF_WTS + (64u << 10);
  const size_t NEED = OFF_CNT + 256;

  if (ws_size >= NEED) {
    u16* xb     = (u16*)(ws + OFF_XB);
    u16* h      = (u16*)(ws + OFF_H);
    u16* w1gb   = (u16*)(ws + OFF_W1G);
    u16* w1ub   = (u16*)(ws + OFF_W1U);
    u16* w2b    = (u16*)(ws + OFF_W2);
    int* ids    = (int*)(ws + OFF_IDS);
    float* wts  = (float*)(ws + OFF_WTS);
    int* counts = (int*)(ws + OFF_CNT);
    int* offs   = counts + 8;
    const int N4 = E_NUM * I_DIM * H_DIM / 4;   // float4 count per weight tensor

    k_prep<<<2048, 256, 0, stream>>>(x, out, xb, counts);
    k_router<<<512, 256, 0, stream>>>(x, gw, counts, ids, wts);
    k_offs<<<1, 64, 0, stream>>>(counts, offs);
    k_cvt<<<4096, 256, 0, stream>>>(w1g, w1gb, N4);
    k_cvt<<<4096, 256, 0, stream>>>(w1u, w1ub, N4);
    k_cvt<<<4096, 256, 0, stream>>>(w2, w2b, N4);
    k_gateup2<<<dim3(I_DIM / BN, T_TOK / BM, E_NUM), 256, 0, stream>>>(xb, w1gb, w1ub, counts, offs, ids, h);
    k_down2<<<dim3((H_DIM / BN) * KS, T_TOK / BM, E_NUM), 256, 0, stream>>>(h, w2b, counts, offs, ids, wts, out);
  } else {
    // fallback: round-1 layout & kernels
    u16* xb     = (u16*)ws;
    u16* h      = (u16*)(ws + 4 * MB);
    int* ids    = (int*)(ws + 4 * MB + 32 * MB);
    float* wts  = (float*)(ws + 4 * MB + 32 * MB + (64u << 10));
    int* counts = (int*)(ws + 4 * MB + 32 * MB + (128u << 10));
    int* offs   = counts + 8;

    k_prep<<<2048, 256, 0, stream>>>(x, out, xb, counts);
    k_router<<<512, 256, 0, stream>>>(x, gw, counts, ids, wts);
    k_offs<<<1, 64, 0, stream>>>(counts, offs);
    k_gateup<<<dim3(I_DIM / BN, T_TOK / BM, E_NUM), 256, 0, stream>>>(xb, w1g, w1u, counts, offs, ids, h);
    k_down<<<dim3(H_DIM / BN, T_TOK / BM, E_NUM), 256, 0, stream>>>(h, w2, counts, offs, ids, wts, out);
  }
}